// Round 2
// baseline (3342.523 us; speedup 1.0000x reference)
//
#include <hip/hip_runtime.h>
#include <math.h>

#define N_NODES 100000
#define N_EDGES 1600000
#define DIM 48

// ---------------- scatter: aggr[dst] += h[src], 48 dims ----------------
// 12 threads per edge, each handles 4 contiguous dims (float4 gather).
__global__ __launch_bounds__(256) void scatter48(
    const float* __restrict__ h, const int* __restrict__ src,
    const int* __restrict__ dst, float* __restrict__ aggr)
{
    unsigned tid = blockIdx.x * blockDim.x + threadIdx.x;
    unsigned e = tid / 12u;
    unsigned q = tid % 12u;
    if (e >= N_EDGES) return;
    int s = src[e];
    int d = dst[e];
    const float4 v = *reinterpret_cast<const float4*>(h + (size_t)s * DIM + q * 4);
    float* a = aggr + (size_t)d * DIM + q * 4;
    atomicAdd(a + 0, v.x);
    atomicAdd(a + 1, v.y);
    atomicAdd(a + 2, v.z);
    atomicAdd(a + 3, v.w);
}

// ---------------- combine: out = aggr @ Wr + br + h @ Wk ----------------
// One thread per (node, j). Weights staged in LDS.
__global__ __launch_bounds__(256) void combine48(
    const float* __restrict__ aggr, const float* __restrict__ h,
    const float* __restrict__ Wr, const float* __restrict__ br,
    const float* __restrict__ Wk, float* __restrict__ out)
{
    __shared__ float sWr[DIM * DIM];
    __shared__ float sWk[DIM * DIM];
    __shared__ float sbr[DIM];
    for (int i = threadIdx.x; i < DIM * DIM; i += blockDim.x) {
        sWr[i] = Wr[i];
        sWk[i] = Wk[i];
    }
    if (threadIdx.x < DIM) sbr[threadIdx.x] = br[threadIdx.x];
    __syncthreads();

    unsigned tid = blockIdx.x * blockDim.x + threadIdx.x;
    if (tid >= (unsigned)N_NODES * DIM) return;
    unsigned node = tid / DIM;
    unsigned j = tid % DIM;
    const float* ar = aggr + (size_t)node * DIM;
    const float* hr = h + (size_t)node * DIM;
    float acc = sbr[j];
#pragma unroll
    for (int k = 0; k < DIM; ++k) {
        acc += ar[k] * sWr[k * DIM + j];
        acc += hr[k] * sWk[k * DIM + j];
    }
    out[tid] = acc;
}

// ---------------- MLP head: sigmoid(relu(h@W0+b0)@W1+b1) ----------------
// One 128-thread block per node; thread j computes hidden unit j.
__global__ __launch_bounds__(128) void mlp_head(
    const float* __restrict__ h, const float* __restrict__ W0,
    const float* __restrict__ b0, const float* __restrict__ W1,
    const float* __restrict__ b1, float* __restrict__ out)
{
    const int node = blockIdx.x;
    const int j = threadIdx.x;  // 0..127
    __shared__ float sh[DIM];
    __shared__ float red[2];
    if (j < DIM) sh[j] = h[(size_t)node * DIM + j];
    __syncthreads();

    float acc = b0[j];
#pragma unroll
    for (int k = 0; k < DIM; ++k) acc += sh[k] * W0[k * 128 + j];
    acc = fmaxf(acc, 0.0f) * W1[j];

    // reduce 128 values: wave64 shuffle reduce, then combine 2 waves via LDS
#pragma unroll
    for (int off = 32; off > 0; off >>= 1) acc += __shfl_down(acc, off);
    if ((j & 63) == 0) red[j >> 6] = acc;
    __syncthreads();
    if (j == 0) {
        float s = red[0] + red[1] + b1[0];
        out[node] = 1.0f / (1.0f + expf(-s));
    }
}

extern "C" void kernel_launch(void* const* d_in, const int* in_sizes, int n_in,
                              void* d_out, int out_size, void* d_ws, size_t ws_size,
                              hipStream_t stream)
{
    const float* x     = (const float*)d_in[0];
    const int*   ei    = (const int*)d_in[1];
    const float* c0_Wr = (const float*)d_in[2];
    const float* c0_br = (const float*)d_in[3];
    const float* c0_Wk = (const float*)d_in[4];
    const float* c1_Wr = (const float*)d_in[5];
    const float* c1_br = (const float*)d_in[6];
    const float* c1_Wk = (const float*)d_in[7];
    const float* c2_Wr = (const float*)d_in[8];
    const float* c2_br = (const float*)d_in[9];
    const float* c2_Wk = (const float*)d_in[10];
    const float* m0_W  = (const float*)d_in[11];
    const float* m0_b  = (const float*)d_in[12];
    const float* m1_W  = (const float*)d_in[13];
    const float* m1_b  = (const float*)d_in[14];
    float* out = (float*)d_out;

    const int* src = ei;
    const int* dst = ei + N_EDGES;

    const size_t feat_elems = (size_t)N_NODES * DIM;
    float* aggr = (float*)d_ws;          // 19.2 MB
    float* hA = aggr + feat_elems;       // 19.2 MB
    float* hB = hA + feat_elems;         // 19.2 MB  -> total 57.6 MB

    const int scatterGrid = (N_EDGES * 12 + 255) / 256;
    const int combineGrid = (int)((feat_elems + 255) / 256);

    // ---- layer 0: x -> hA ----
    hipMemsetAsync(aggr, 0, feat_elems * sizeof(float), stream);
    scatter48<<<scatterGrid, 256, 0, stream>>>(x, src, dst, aggr);
    combine48<<<combineGrid, 256, 0, stream>>>(aggr, x, c0_Wr, c0_br, c0_Wk, hA);

    // ---- layer 1: hA -> hB ----
    hipMemsetAsync(aggr, 0, feat_elems * sizeof(float), stream);
    scatter48<<<scatterGrid, 256, 0, stream>>>(hA, src, dst, aggr);
    combine48<<<combineGrid, 256, 0, stream>>>(aggr, hA, c1_Wr, c1_br, c1_Wk, hB);

    // ---- layer 2: hB -> hA ----
    hipMemsetAsync(aggr, 0, feat_elems * sizeof(float), stream);
    scatter48<<<scatterGrid, 256, 0, stream>>>(hB, src, dst, aggr);
    combine48<<<combineGrid, 256, 0, stream>>>(aggr, hB, c2_Wr, c2_br, c2_Wk, hA);

    // ---- MLP head ----
    mlp_head<<<N_NODES, 128, 0, stream>>>(hA, m0_W, m0_b, m1_W, m1_b, out);
}

// Round 5
// 704.499 us; speedup vs baseline: 4.7445x; 4.7445x over previous
//
#include <hip/hip_runtime.h>
#include <math.h>

#define N_NODES 100000
#define N_EDGES 1600000
#define DIM 48
#define NPB 16          // nodes per block (fused layer)
#define THREADS 192     // 16 nodes x 12 lanes
#define NODE_BLOCKS ((N_NODES + 255) / 256)   // 391
#define EDGE_BLOCKS ((N_EDGES + 255) / 256)   // 6250

// ============ CSR build ============
__global__ __launch_bounds__(256) void hist_deg(
    const int* __restrict__ dst, int* __restrict__ deg)
{
    unsigned e = blockIdx.x * 256u + threadIdx.x;
    if (e < N_EDGES) atomicAdd(&deg[dst[e]], 1);
}

__global__ __launch_bounds__(256) void block_sums(
    const int* __restrict__ deg, int* __restrict__ bsum)
{
    __shared__ int r[256];
    unsigned t = threadIdx.x;
    unsigned i = blockIdx.x * 256u + t;
    r[t] = (i < N_NODES) ? deg[i] : 0;
    __syncthreads();
    for (int s = 128; s > 0; s >>= 1) {
        if (t < (unsigned)s) r[t] += r[t + s];
        __syncthreads();
    }
    if (t == 0) bsum[blockIdx.x] = r[0];
}

// single block, 512 threads: exclusive scan of bsum[0..NODE_BLOCKS)
__global__ __launch_bounds__(512) void scan_block_sums(
    const int* __restrict__ bsum, int* __restrict__ bsum_ex)
{
    __shared__ int s[512];
    unsigned t = threadIdx.x;
    int v = (t < NODE_BLOCKS) ? bsum[t] : 0;
    s[t] = v;
    __syncthreads();
    for (int off = 1; off < 512; off <<= 1) {
        int u = (t >= (unsigned)off) ? s[t - off] : 0;
        __syncthreads();
        s[t] += u;
        __syncthreads();
    }
    bsum_ex[t] = s[t] - v;   // exclusive
}

__global__ __launch_bounds__(256) void write_offsets(
    const int* __restrict__ deg, const int* __restrict__ bsum_ex,
    int* __restrict__ row_off, int* __restrict__ cursor)
{
    __shared__ int s[256];
    unsigned t = threadIdx.x;
    unsigned i = blockIdx.x * 256u + t;
    int v = (i < N_NODES) ? deg[i] : 0;
    s[t] = v;
    __syncthreads();
    for (int off = 1; off < 256; off <<= 1) {
        int u = (t >= (unsigned)off) ? s[t - off] : 0;
        __syncthreads();
        s[t] += u;
        __syncthreads();
    }
    if (i < N_NODES) {
        int o = bsum_ex[blockIdx.x] + s[t] - v;  // exclusive prefix
        row_off[i] = o;
        cursor[i] = o;
    }
    if (i == 0) row_off[N_NODES] = N_EDGES;
}

__global__ __launch_bounds__(256) void fill_csr(
    const int* __restrict__ src, const int* __restrict__ dst,
    int* __restrict__ cursor, int* __restrict__ csr_src)
{
    unsigned e = blockIdx.x * 256u + threadIdx.x;
    if (e >= N_EDGES) return;
    int pos = atomicAdd(&cursor[dst[e]], 1);
    csr_src[pos] = src[e];
}

// ============ fused layer: out = (CSR-gather-sum of h) @ Wr + br + h @ Wk ============
// 192 threads = 16 nodes x 12 lanes. Phase 1: gather to LDS. Phase 2: dense combine.
__global__ __launch_bounds__(THREADS) void fused_layer(
    const float* __restrict__ h, const int* __restrict__ row_off,
    const int* __restrict__ csr_src,
    const float* __restrict__ Wr, const float* __restrict__ br,
    const float* __restrict__ Wk, float* __restrict__ out)
{
    __shared__ float sWr[DIM * DIM];
    __shared__ float sWk[DIM * DIM];
    __shared__ float sbr[DIM];
    __shared__ float sAg[NPB][DIM];
    __shared__ float sH[NPB][DIM];

    // stage weights (once per block)
    for (int i = threadIdx.x; i < DIM * DIM; i += THREADS) {
        sWr[i] = Wr[i];
        sWk[i] = Wk[i];
    }
    if (threadIdx.x < DIM) sbr[threadIdx.x] = br[threadIdx.x];

    const unsigned ln = threadIdx.x / 12u;   // 0..15
    const unsigned q  = threadIdx.x % 12u;   // 0..11
    const unsigned node = blockIdx.x * NPB + ln;  // grid exact: 6250*16 = 100000

    // stage own h row
    const float4 hv = *reinterpret_cast<const float4*>(h + (size_t)node * DIM + q * 4);
    *reinterpret_cast<float4*>(&sH[ln][q * 4]) = hv;

    // CSR gather-sum
    const int beg = row_off[node];
    const int end = row_off[node + 1];
    float4 acc = make_float4(0.f, 0.f, 0.f, 0.f);
    for (int i = beg; i < end; ++i) {
        int s = csr_src[i];
        const float4 v = *reinterpret_cast<const float4*>(h + (size_t)s * DIM + q * 4);
        acc.x += v.x; acc.y += v.y; acc.z += v.z; acc.w += v.w;
    }
    *reinterpret_cast<float4*>(&sAg[ln][q * 4]) = acc;
    __syncthreads();

    // dense combine: 16*48 = 768 jobs over 192 threads -> 4 iters
#pragma unroll
    for (int it = 0; it < 4; ++it) {
        unsigned idx = it * THREADS + threadIdx.x;
        unsigned l2 = idx / DIM;   // 0..15
        unsigned j  = idx % DIM;   // 0..47
        float a = sbr[j];
#pragma unroll
        for (int k = 0; k < DIM; ++k) {
            a += sAg[l2][k] * sWr[k * DIM + j];
            a += sH[l2][k] * sWk[k * DIM + j];
        }
        out[(size_t)(blockIdx.x * NPB + l2) * DIM + j] = a;
    }
}

// ============ MLP head: sigmoid(relu(h@W0+b0)@W1+b1) ============
__global__ __launch_bounds__(128) void mlp_head(
    const float* __restrict__ h, const float* __restrict__ W0,
    const float* __restrict__ b0, const float* __restrict__ W1,
    const float* __restrict__ b1, float* __restrict__ out)
{
    const int node = blockIdx.x;
    const int j = threadIdx.x;  // 0..127
    __shared__ float sh[DIM];
    __shared__ float red[2];
    if (j < DIM) sh[j] = h[(size_t)node * DIM + j];
    __syncthreads();

    float acc = b0[j];
#pragma unroll
    for (int k = 0; k < DIM; ++k) acc += sh[k] * W0[k * 128 + j];
    acc = fmaxf(acc, 0.0f) * W1[j];

#pragma unroll
    for (int off = 32; off > 0; off >>= 1) acc += __shfl_down(acc, off);
    if ((j & 63) == 0) red[j >> 6] = acc;
    __syncthreads();
    if (j == 0) {
        float s = red[0] + red[1] + b1[0];
        out[node] = 1.0f / (1.0f + expf(-s));
    }
}

extern "C" void kernel_launch(void* const* d_in, const int* in_sizes, int n_in,
                              void* d_out, int out_size, void* d_ws, size_t ws_size,
                              hipStream_t stream)
{
    const float* x     = (const float*)d_in[0];
    const int*   ei    = (const int*)d_in[1];
    const float* c0_Wr = (const float*)d_in[2];
    const float* c0_br = (const float*)d_in[3];
    const float* c0_Wk = (const float*)d_in[4];
    const float* c1_Wr = (const float*)d_in[5];
    const float* c1_br = (const float*)d_in[6];
    const float* c1_Wk = (const float*)d_in[7];
    const float* c2_Wr = (const float*)d_in[8];
    const float* c2_br = (const float*)d_in[9];
    const float* c2_Wk = (const float*)d_in[10];
    const float* m0_W  = (const float*)d_in[11];
    const float* m0_b  = (const float*)d_in[12];
    const float* m1_W  = (const float*)d_in[13];
    const float* m1_b  = (const float*)d_in[14];
    float* out = (float*)d_out;

    const int* src = ei;
    const int* dst = ei + N_EDGES;

    const size_t feat_elems = (size_t)N_NODES * DIM;
    char* w = (char*)d_ws;
    float* hA      = (float*)w;                   w += feat_elems * 4;       // 19.2 MB
    float* hB      = (float*)w;                   w += feat_elems * 4;       // 19.2 MB
    int*   deg     = (int*)w;                     w += N_NODES * 4;
    int*   cursor  = (int*)w;                     w += N_NODES * 4;
    int*   row_off = (int*)w;                     w += (N_NODES + 1) * 4;
    int*   bsum    = (int*)w;                     w += 512 * 4;
    int*   bsum_ex = (int*)w;                     w += 512 * 4;
    int*   csr_src = (int*)w;                     w += (size_t)N_EDGES * 4;  // 6.4 MB

    // ---- CSR build (once; reused by all 3 layers) ----
    hipMemsetAsync(deg, 0, N_NODES * sizeof(int), stream);
    hist_deg<<<EDGE_BLOCKS, 256, 0, stream>>>(dst, deg);
    block_sums<<<NODE_BLOCKS, 256, 0, stream>>>(deg, bsum);
    scan_block_sums<<<1, 512, 0, stream>>>(bsum, bsum_ex);
    write_offsets<<<NODE_BLOCKS, 256, 0, stream>>>(deg, bsum_ex, row_off, cursor);
    fill_csr<<<EDGE_BLOCKS, 256, 0, stream>>>(src, dst, cursor, csr_src);

    const int fusedGrid = N_NODES / NPB;  // 6250, exact

    // ---- layer 0: x -> hA ----
    fused_layer<<<fusedGrid, THREADS, 0, stream>>>(x, row_off, csr_src, c0_Wr, c0_br, c0_Wk, hA);
    // ---- layer 1: hA -> hB ----
    fused_layer<<<fusedGrid, THREADS, 0, stream>>>(hA, row_off, csr_src, c1_Wr, c1_br, c1_Wk, hB);
    // ---- layer 2: hB -> hA ----
    fused_layer<<<fusedGrid, THREADS, 0, stream>>>(hB, row_off, csr_src, c2_Wr, c2_br, c2_Wk, hA);

    // ---- MLP head ----
    mlp_head<<<N_NODES, 128, 0, stream>>>(hA, m0_W, m0_b, m1_W, m1_b, out);
}